// Round 1
// baseline (1944.035 us; speedup 1.0000x reference)
//
#include <hip/hip_runtime.h>
#include <cmath>

#define D_MODEL 1024
#define N_HEADS 16
#define HEAD_DIM 64
#define SEQ 1024
#define BATCH 4
#define FF_DIM 4096
#define IN_DIM 256
#define N_LAYERS 6
#define N_CLS 10

typedef __bf16 bf16x8 __attribute__((ext_vector_type(8)));
typedef float f32x4 __attribute__((ext_vector_type(4)));
typedef unsigned short u16x8 __attribute__((ext_vector_type(8)));

__device__ __forceinline__ unsigned short f2bf(float f) {
    unsigned int u = __float_as_uint(f);
    u += 0x7fffu + ((u >> 16) & 1u);
    return (unsigned short)(u >> 16);
}

__device__ __forceinline__ void gll16(const void* g, void* l) {
    __builtin_amdgcn_global_load_lds((const __attribute__((address_space(1))) void*)g,
                                     (__attribute__((address_space(3))) void*)l, 16, 0, 0);
}

// ---------------------------------------------------------------------------
// f32 -> bf16 convert (vectorized)
// ---------------------------------------------------------------------------
__global__ __launch_bounds__(256)
void cvt_f32_bf16(const float* __restrict__ src, unsigned short* __restrict__ dst, int n) {
    int i = (blockIdx.x * 256 + threadIdx.x) * 4;
    if (i + 4 <= n) {
        float4 v = *(const float4*)(src + i);
        ushort4 o;
        o.x = f2bf(v.x); o.y = f2bf(v.y); o.z = f2bf(v.z); o.w = f2bf(v.w);
        *(ushort4*)(dst + i) = o;
    }
}

// ---------------------------------------------------------------------------
// NT GEMM: A[M][K] bf16 row-major, B[N][K] bf16 row-major, C = A*B^T + bias
// m97 structure: 128x128 tile, BK=64, 4 waves (2x2), global_load_lds w=16.
// Optional f32 and/or bf16 outputs, optional ReLU.
// ---------------------------------------------------------------------------
__global__ __launch_bounds__(256, 2)
void gemm_bt(const unsigned short* __restrict__ A, const unsigned short* __restrict__ B,
             const float* __restrict__ bias,
             float* __restrict__ Cf, unsigned short* __restrict__ Cb,
             int M, int N, int K, int relu)
{
    __shared__ __align__(16) unsigned short lsA[128 * 64];
    __shared__ __align__(16) unsigned short lsB[128 * 64];

    const int nbc  = N >> 7;
    const int brow = blockIdx.x / nbc;
    const int bcol = blockIdx.x % nbc;
    const int w = threadIdx.x >> 6, l = threadIdx.x & 63;
    const int wr = w >> 1, wc = w & 1;
    const int lr = l & 15, lg = l >> 4;

    f32x4 acc[4][4] = {};

    const unsigned short* Ab = A + (size_t)brow * 128 * K;
    const unsigned short* Bb = B + (size_t)bcol * 128 * K;

    for (int k0 = 0; k0 < K; k0 += 64) {
        #pragma unroll
        for (int i = 0; i < 4; ++i) {
            int chunk = i * 4 + w;            // 0..15, 1KB chunks
            int e = chunk * 512 + l * 8;      // element offset in tile
            int row = e >> 6, col = e & 63;
            gll16(Ab + (size_t)row * K + k0 + col, &lsA[chunk * 512]);
            gll16(Bb + (size_t)row * K + k0 + col, &lsB[chunk * 512]);
        }
        __syncthreads();
        #pragma unroll
        for (int ks = 0; ks < 2; ++ks) {
            bf16x8 af[4], bfr[4];
            #pragma unroll
            for (int m = 0; m < 4; ++m)
                af[m] = *(const bf16x8*)&lsA[(wr * 64 + m * 16 + lr) * 64 + ks * 32 + lg * 8];
            #pragma unroll
            for (int n = 0; n < 4; ++n)
                bfr[n] = *(const bf16x8*)&lsB[(wc * 64 + n * 16 + lr) * 64 + ks * 32 + lg * 8];
            #pragma unroll
            for (int m = 0; m < 4; ++m)
                #pragma unroll
                for (int n = 0; n < 4; ++n)
                    acc[m][n] = __builtin_amdgcn_mfma_f32_16x16x32_bf16(af[m], bfr[n], acc[m][n], 0, 0, 0);
        }
        __syncthreads();
    }

    const int crow0 = brow * 128 + wr * 64;
    const int ccol0 = bcol * 128 + wc * 64;
    #pragma unroll
    for (int n = 0; n < 4; ++n) {
        int col = ccol0 + n * 16 + lr;
        float bv = bias ? bias[col] : 0.0f;
        #pragma unroll
        for (int m = 0; m < 4; ++m) {
            int row0 = crow0 + m * 16 + lg * 4;
            #pragma unroll
            for (int j = 0; j < 4; ++j) {
                float v = acc[m][n][j] + bv;
                if (relu) v = fmaxf(v, 0.0f);
                size_t idx = (size_t)(row0 + j) * N + col;
                if (Cf) Cf[idx] = v;
                if (Cb) Cb[idx] = f2bf(v);
            }
        }
    }
}

// ---------------------------------------------------------------------------
// Flash attention with scalar-slope ALiBi.
// Grid: B*H*(SEQ/64) blocks, 256 threads (4 waves x 16 q-rows).
// qkv: [B][T][3*D] bf16 (q at +0, k at +D, v at +2D within each row).
// out: [B][T][D] bf16.
// ---------------------------------------------------------------------------
__global__ __launch_bounds__(256, 2)
void attn_alibi(const unsigned short* __restrict__ qkv,
                unsigned short* __restrict__ out,
                float slope)
{
    const int qt = blockIdx.x & 15;
    const int bh = blockIdx.x >> 4;
    const int h  = bh & (N_HEADS - 1);
    const int b  = bh >> 4;
    const int w  = threadIdx.x >> 6, l = threadIdx.x & 63;
    const int lr = l & 15, lg = l >> 4;

    __shared__ __align__(16) unsigned short lsK[64 * 64];
    __shared__ __align__(16) unsigned short lsVt[64 * 64];
    __shared__ __align__(16) unsigned short lsP[4 * 16 * 64];

    const size_t rs = 3 * D_MODEL;
    const unsigned short* base = qkv + (size_t)b * SEQ * rs;
    const int qrow_w = qt * 64 + w * 16;
    const float scale = 0.125f;   // 1/sqrt(64)

    // Q fragments stay in registers the whole kernel
    bf16x8 aq[2];
    #pragma unroll
    for (int ks = 0; ks < 2; ++ks)
        aq[ks] = *(const bf16x8*)(base + (size_t)(qrow_w + lr) * rs + h * HEAD_DIM + ks * 32 + lg * 8);

    float m_run[4] = {-1e30f, -1e30f, -1e30f, -1e30f};
    float s_run[4] = {0.f, 0.f, 0.f, 0.f};
    f32x4 oacc[4] = {};

    for (int kt = 0; kt < SEQ / 64; ++kt) {
        // --- stage K tile via global_load_lds with pre-swizzled global col ---
        #pragma unroll
        for (int i = 0; i < 2; ++i) {
            int chunk = i * 4 + w;            // 0..7
            int e = chunk * 512 + l * 8;
            int row = e >> 6, c = e & 63;
            int gcol = c ^ ((row & 7) << 3);  // 8-elem-block XOR swizzle
            gll16(base + (size_t)(kt * 64 + row) * rs + D_MODEL + h * HEAD_DIM + gcol,
                  &lsK[chunk * 512]);
        }
        // --- stage V^T: per-lane gather (L2-resident), conflict-free swizzled writes ---
        #pragma unroll
        for (int i = 0; i < 2; ++i) {
            int oct = i * 4 + w;              // d-octet 0..7
            int kj  = l;                      // 0..63
            u16x8 v = *(const u16x8*)(base + (size_t)(kt * 64 + kj) * rs + 2 * D_MODEL + h * HEAD_DIM + oct * 8);
            #pragma unroll
            for (int jj = 0; jj < 8; ++jj) {
                int row = oct * 8 + jj;       // d index
                lsVt[row * 64 + (kj ^ ((row & 7) << 3))] = v[jj];
            }
        }
        __syncthreads();

        // --- QK^T ---
        f32x4 sacc[4] = {};
        #pragma unroll
        for (int ks = 0; ks < 2; ++ks) {
            #pragma unroll
            for (int n = 0; n < 4; ++n) {
                int row = n * 16 + lr;
                bf16x8 bk = *(const bf16x8*)&lsK[row * 64 + ((ks * 32 + lg * 8) ^ ((row & 7) << 3))];
                sacc[n] = __builtin_amdgcn_mfma_f32_16x16x32_bf16(aq[ks], bk, sacc[n], 0, 0, 0);
            }
        }

        // --- online softmax (scale + ALiBi), P -> LDS (per-wave region) ---
        #pragma unroll
        for (int j = 0; j < 4; ++j) {
            float qi = (float)(qt * 64 + w * 16 + lg * 4 + j);
            float sv[4]; float mx = -1e30f;
            #pragma unroll
            for (int n = 0; n < 4; ++n) {
                float kjf = (float)(kt * 64 + n * 16 + lr);
                float val = sacc[n][j] * scale - slope * fabsf(qi - kjf);
                sv[n] = val;
                mx = fmaxf(mx, val);
            }
            #pragma unroll
            for (int d = 1; d < 16; d <<= 1)
                mx = fmaxf(mx, __shfl_xor(mx, d));
            float mnew = fmaxf(m_run[j], mx);
            float corr = __expf(m_run[j] - mnew);
            float psum = 0.f;
            #pragma unroll
            for (int n = 0; n < 4; ++n) {
                float p = __expf(sv[n] - mnew);
                sv[n] = p;
                psum += p;
            }
            #pragma unroll
            for (int d = 1; d < 16; d <<= 1)
                psum += __shfl_xor(psum, d);
            s_run[j] = s_run[j] * corr + psum;
            m_run[j] = mnew;
            #pragma unroll
            for (int nd = 0; nd < 4; ++nd)
                oacc[nd][j] *= corr;
            int prow = lg * 4 + j;
            #pragma unroll
            for (int n = 0; n < 4; ++n)
                lsP[w * 1024 + prow * 64 + ((n * 16 + lr) ^ ((prow & 7) << 3))] = f2bf(sv[n]);
        }

        // --- PV (A = P from own-wave LDS region, B = V^T) ---
        #pragma unroll
        for (int ks = 0; ks < 2; ++ks) {
            bf16x8 ap = *(const bf16x8*)&lsP[w * 1024 + lr * 64 + ((ks * 32 + lg * 8) ^ ((lr & 7) << 3))];
            #pragma unroll
            for (int nd = 0; nd < 4; ++nd) {
                int row = nd * 16 + lr;
                bf16x8 bv = *(const bf16x8*)&lsVt[row * 64 + ((ks * 32 + lg * 8) ^ ((row & 7) << 3))];
                oacc[nd] = __builtin_amdgcn_mfma_f32_16x16x32_bf16(ap, bv, oacc[nd], 0, 0, 0);
            }
        }
        __syncthreads();
    }

    // --- normalize + write O ---
    #pragma unroll
    for (int j = 0; j < 4; ++j) {
        float inv = 1.0f / s_run[j];
        int qrow = qrow_w + lg * 4 + j;
        #pragma unroll
        for (int nd = 0; nd < 4; ++nd) {
            int d = nd * 16 + lr;
            out[((size_t)b * SEQ + qrow) * D_MODEL + h * HEAD_DIM + d] = f2bf(oacc[nd][j] * inv);
        }
    }
}

// ---------------------------------------------------------------------------
// h = LN(resid + delta) * g + beta ; writes f32 and bf16 views.
// One block per row (D=1024, 256 threads x 4 elems).
// ---------------------------------------------------------------------------
__global__ __launch_bounds__(256)
void add_ln(const float* __restrict__ resid, const float* __restrict__ delta,
            const float* __restrict__ g, const float* __restrict__ beta,
            float* __restrict__ out_f, unsigned short* __restrict__ out_b)
{
    const int row = blockIdx.x;
    const int t = threadIdx.x;
    const int w = t >> 6, l = t & 63;
    __shared__ float red[8];
    const size_t off = (size_t)row * D_MODEL + t * 4;

    float4 rv = *(const float4*)(resid + off);
    float4 dv = *(const float4*)(delta + off);
    float x0 = rv.x + dv.x, x1 = rv.y + dv.y, x2 = rv.z + dv.z, x3 = rv.w + dv.w;
    float s  = x0 + x1 + x2 + x3;
    float s2 = x0 * x0 + x1 * x1 + x2 * x2 + x3 * x3;
    #pragma unroll
    for (int d = 1; d < 64; d <<= 1) {
        s  += __shfl_xor(s, d);
        s2 += __shfl_xor(s2, d);
    }
    if (l == 0) { red[w] = s; red[4 + w] = s2; }
    __syncthreads();
    s  = red[0] + red[1] + red[2] + red[3];
    s2 = red[4] + red[5] + red[6] + red[7];
    float mu  = s * (1.0f / D_MODEL);
    float var = s2 * (1.0f / D_MODEL) - mu * mu;
    float rsq = rsqrtf(var + 1e-5f);

    float4 gv = *(const float4*)(g + t * 4);
    float4 bv = *(const float4*)(beta + t * 4);
    float y0 = (x0 - mu) * rsq * gv.x + bv.x;
    float y1 = (x1 - mu) * rsq * gv.y + bv.y;
    float y2 = (x2 - mu) * rsq * gv.z + bv.z;
    float y3 = (x3 - mu) * rsq * gv.w + bv.w;
    float4 of; of.x = y0; of.y = y1; of.z = y2; of.w = y3;
    *(float4*)(out_f + off) = of;
    ushort4 ob; ob.x = f2bf(y0); ob.y = f2bf(y1); ob.z = f2bf(y2); ob.w = f2bf(y3);
    *(ushort4*)(out_b + off) = ob;
}

// ---------------------------------------------------------------------------
// Head: out[b][c] = dot(h[b, T-1, :], head_w[c, :]) + head_b[c]  (f32)
// 1 block, 4 waves (one per batch row).
// ---------------------------------------------------------------------------
__global__ __launch_bounds__(256)
void head_kernel(const float* __restrict__ h, const float* __restrict__ hw,
                 const float* __restrict__ hb, float* __restrict__ out)
{
    const int wv = threadIdx.x >> 6, l = threadIdx.x & 63;
    const float* hr = h + ((size_t)wv * SEQ + (SEQ - 1)) * D_MODEL;
    for (int c = 0; c < N_CLS; ++c) {
        float s = 0.f;
        for (int k = l; k < D_MODEL; k += 64)
            s += hr[k] * hw[c * D_MODEL + k];
        #pragma unroll
        for (int d = 1; d < 64; d <<= 1)
            s += __shfl_xor(s, d);
        if (l == 0) out[wv * N_CLS + c] = s + hb[c];
    }
}

// ---------------------------------------------------------------------------
extern "C" void kernel_launch(void* const* d_in, const int* in_sizes, int n_in,
                              void* d_out, int out_size, void* d_ws, size_t ws_size,
                              hipStream_t stream)
{
    const float* x     = (const float*)d_in[0];
    const float* in_w  = (const float*)d_in[1];
    const float* in_b  = (const float*)d_in[2];
    const float* Wqkv  = (const float*)d_in[3];
    const float* bqkv  = (const float*)d_in[4];
    const float* Wo    = (const float*)d_in[5];
    const float* bo    = (const float*)d_in[6];
    const float* ln1g  = (const float*)d_in[7];
    const float* ln1b  = (const float*)d_in[8];
    const float* ln2g  = (const float*)d_in[9];
    const float* ln2b  = (const float*)d_in[10];
    const float* W1    = (const float*)d_in[11];
    const float* b1    = (const float*)d_in[12];
    const float* W2    = (const float*)d_in[13];
    const float* b2    = (const float*)d_in[14];
    const float* headw = (const float*)d_in[15];
    const float* headb = (const float*)d_in[16];
    float* out = (float*)d_out;

    char* ws = (char*)d_ws;
    size_t off = 0;
    auto alloc = [&](size_t bytes) -> void* {
        void* p = ws + off;
        off += (bytes + 255) & ~(size_t)255;
        return p;
    };
    const int MT = BATCH * SEQ;  // 4096

    unsigned short* x_bf   = (unsigned short*)alloc((size_t)MT * IN_DIM * 2);
    float*          h_f    = (float*)alloc((size_t)MT * D_MODEL * 4);
    unsigned short* h_bf   = (unsigned short*)alloc((size_t)MT * D_MODEL * 2);
    unsigned short* qkv_bf = (unsigned short*)alloc((size_t)MT * 3 * D_MODEL * 2);
    unsigned short* att_bf = (unsigned short*)alloc((size_t)MT * D_MODEL * 2);
    unsigned short* ff_bf  = (unsigned short*)alloc((size_t)MT * FF_DIM * 2);
    float*          tmp_f  = (float*)alloc((size_t)MT * D_MODEL * 4);
    unsigned short* win_bf = (unsigned short*)alloc((size_t)D_MODEL * IN_DIM * 2);
    unsigned short* wq_bf  = (unsigned short*)alloc((size_t)3 * D_MODEL * D_MODEL * 2);
    unsigned short* wo_bf  = (unsigned short*)alloc((size_t)D_MODEL * D_MODEL * 2);
    unsigned short* w1_bf  = (unsigned short*)alloc((size_t)FF_DIM * D_MODEL * 2);
    unsigned short* w2_bf  = (unsigned short*)alloc((size_t)D_MODEL * FF_DIM * 2);

    // ALiBi scalar slope = mean over heads of 2^(-8*i/H), i=1..H
    double ssum = 0.0;
    for (int i = 1; i <= N_HEADS; ++i) ssum += pow(2.0, -8.0 * i / N_HEADS);
    const float slope = (float)(ssum / N_HEADS);

    auto cvt = [&](const float* s, unsigned short* d, int n) {
        cvt_f32_bf16<<<n / 1024, 256, 0, stream>>>(s, d, n);
    };

    // input projection
    cvt(x, x_bf, MT * IN_DIM);
    cvt(in_w, win_bf, D_MODEL * IN_DIM);
    gemm_bt<<<(MT / 128) * (D_MODEL / 128), 256, 0, stream>>>(
        x_bf, win_bf, in_b, h_f, h_bf, MT, D_MODEL, IN_DIM, 0);

    for (int layer = 0; layer < N_LAYERS; ++layer) {
        cvt(Wqkv + (size_t)layer * 3 * D_MODEL * D_MODEL, wq_bf, 3 * D_MODEL * D_MODEL);
        cvt(Wo   + (size_t)layer * D_MODEL * D_MODEL,     wo_bf, D_MODEL * D_MODEL);
        cvt(W1   + (size_t)layer * FF_DIM * D_MODEL,      w1_bf, FF_DIM * D_MODEL);
        cvt(W2   + (size_t)layer * D_MODEL * FF_DIM,      w2_bf, D_MODEL * FF_DIM);

        gemm_bt<<<(MT / 128) * (3 * D_MODEL / 128), 256, 0, stream>>>(
            h_bf, wq_bf, bqkv + (size_t)layer * 3 * D_MODEL,
            nullptr, qkv_bf, MT, 3 * D_MODEL, D_MODEL, 0);

        attn_alibi<<<BATCH * N_HEADS * (SEQ / 64), 256, 0, stream>>>(qkv_bf, att_bf, slope);

        gemm_bt<<<(MT / 128) * (D_MODEL / 128), 256, 0, stream>>>(
            att_bf, wo_bf, bo + (size_t)layer * D_MODEL,
            tmp_f, nullptr, MT, D_MODEL, D_MODEL, 0);

        add_ln<<<MT, 256, 0, stream>>>(h_f, tmp_f,
            ln1g + (size_t)layer * D_MODEL, ln1b + (size_t)layer * D_MODEL, h_f, h_bf);

        gemm_bt<<<(MT / 128) * (FF_DIM / 128), 256, 0, stream>>>(
            h_bf, w1_bf, b1 + (size_t)layer * FF_DIM,
            nullptr, ff_bf, MT, FF_DIM, D_MODEL, 1);

        gemm_bt<<<(MT / 128) * (D_MODEL / 128), 256, 0, stream>>>(
            ff_bf, w2_bf, b2 + (size_t)layer * D_MODEL,
            tmp_f, nullptr, MT, D_MODEL, FF_DIM, 0);

        add_ln<<<MT, 256, 0, stream>>>(h_f, tmp_f,
            ln2g + (size_t)layer * D_MODEL, ln2b + (size_t)layer * D_MODEL, h_f, h_bf);
    }

    head_kernel<<<1, 256, 0, stream>>>(h_f, headw, headb, out);
}

// Round 2
// 1898.552 us; speedup vs baseline: 1.0240x; 1.0240x over previous
//
#include <hip/hip_runtime.h>
#include <cmath>

#define D_MODEL 1024
#define N_HEADS 16
#define HEAD_DIM 64
#define SEQ 1024
#define BATCH 4
#define FF_DIM 4096
#define IN_DIM 256
#define N_LAYERS 6
#define N_CLS 10

typedef __bf16 bf16x8 __attribute__((ext_vector_type(8)));
typedef float f32x4 __attribute__((ext_vector_type(4)));
typedef unsigned short u16x8 __attribute__((ext_vector_type(8)));

__device__ __forceinline__ unsigned short f2bf(float f) {
    unsigned int u = __float_as_uint(f);
    u += 0x7fffu + ((u >> 16) & 1u);
    return (unsigned short)(u >> 16);
}

__device__ __forceinline__ void gll16(const void* g, void* l) {
    __builtin_amdgcn_global_load_lds((const __attribute__((address_space(1))) void*)g,
                                     (__attribute__((address_space(3))) void*)l, 16, 0, 0);
}

// ---------------------------------------------------------------------------
// f32 -> bf16 convert (vectorized)
// ---------------------------------------------------------------------------
__global__ __launch_bounds__(256)
void cvt_f32_bf16(const float* __restrict__ src, unsigned short* __restrict__ dst, int n) {
    int i = (blockIdx.x * 256 + threadIdx.x) * 4;
    if (i + 4 <= n) {
        float4 v = *(const float4*)(src + i);
        ushort4 o;
        o.x = f2bf(v.x); o.y = f2bf(v.y); o.z = f2bf(v.z); o.w = f2bf(v.w);
        *(ushort4*)(dst + i) = o;
    }
}

// ---------------------------------------------------------------------------
// NT GEMM: A[M][lda] bf16 row-major, B[N][lda] bf16 row-major, C = A*B^T + bias
// 128x128 tile, BK=64, 4 waves (2x2), global_load_lds w=16,
// 2-phase explicit double-buffer (one barrier per K-step, loads in flight
// across MFMA), bijective XCD swizzle (m204), optional split-K via blockIdx.y
// (partial f32 slabs, bias added in slab 0 only).
// ---------------------------------------------------------------------------
__global__ __launch_bounds__(256, 2)
void gemm_bt(const unsigned short* __restrict__ A, const unsigned short* __restrict__ B,
             const float* __restrict__ bias,
             float* __restrict__ Cf, unsigned short* __restrict__ Cb,
             int N, int lda, int klen, int relu, size_t slab_stride)
{
    __shared__ __align__(16) unsigned short lsA[2][128 * 64];
    __shared__ __align__(16) unsigned short lsB[2][128 * 64];

    const int nbc = N >> 7;
    // bijective XCD-aware swizzle (m204)
    const int nwg = gridDim.x;
    const int orig = blockIdx.x;
    const int xcd = orig & 7, lid = orig >> 3;
    const int q = nwg >> 3, r = nwg & 7;
    const int wgid = (xcd < r ? xcd * (q + 1) : r * (q + 1) + (xcd - r) * q) + lid;
    const int brow = wgid / nbc;
    const int bcol = wgid % nbc;
    const int kpart = blockIdx.y;

    const int w = threadIdx.x >> 6, l = threadIdx.x & 63;
    const int wr = w >> 1, wc = w & 1;
    const int lr = l & 15, lg = l >> 4;

    f32x4 acc[4][4] = {};

    const unsigned short* Ab = A + (size_t)brow * 128 * lda + (size_t)kpart * klen;
    const unsigned short* Bb = B + (size_t)bcol * 128 * lda + (size_t)kpart * klen;
    float* Cfp = Cf ? Cf + (size_t)kpart * slab_stride : nullptr;
    const float* biasp = (kpart == 0) ? bias : nullptr;

    auto stage = [&](int buf, int k0) {
        #pragma unroll
        for (int i = 0; i < 4; ++i) {
            int chunk = i * 4 + w;            // 0..15, 1KB chunks
            int e = chunk * 512 + l * 8;      // element offset in tile
            int row = e >> 6, col = e & 63;
            gll16(Ab + (size_t)row * lda + k0 + col, &lsA[buf][chunk * 512]);
            gll16(Bb + (size_t)row * lda + k0 + col, &lsB[buf][chunk * 512]);
        }
    };

    auto compute = [&](int buf) {
        #pragma unroll
        for (int ks = 0; ks < 2; ++ks) {
            bf16x8 af[4], bfr[4];
            #pragma unroll
            for (int m = 0; m < 4; ++m)
                af[m] = *(const bf16x8*)&lsA[buf][(wr * 64 + m * 16 + lr) * 64 + ks * 32 + lg * 8];
            #pragma unroll
            for (int n = 0; n < 4; ++n)
                bfr[n] = *(const bf16x8*)&lsB[buf][(wc * 64 + n * 16 + lr) * 64 + ks * 32 + lg * 8];
            #pragma unroll
            for (int m = 0; m < 4; ++m)
                #pragma unroll
                for (int n = 0; n < 4; ++n)
                    acc[m][n] = __builtin_amdgcn_mfma_f32_16x16x32_bf16(af[m], bfr[n], acc[m][n], 0, 0, 0);
        }
    };

    const int KT = klen >> 6;
    stage(0, 0);
    __syncthreads();          // drains vmcnt before anyone reads buf 0
    int cur = 0;
    for (int kt = 0; kt < KT - 1; ++kt) {
        stage(cur ^ 1, (kt + 1) * 64);   // next tile's loads stay in flight...
        __builtin_amdgcn_s_setprio(1);
        compute(cur);                    // ...while MFMA runs on current tile
        __builtin_amdgcn_s_setprio(0);
        __syncthreads();                 // single drain+barrier per K-step
        cur ^= 1;
    }
    compute(cur);                        // last tile: no prefetch

    const int crow0 = brow * 128 + wr * 64;
    const int ccol0 = bcol * 128 + wc * 64;
    #pragma unroll
    for (int n = 0; n < 4; ++n) {
        int col = ccol0 + n * 16 + lr;
        float bv = biasp ? biasp[col] : 0.0f;
        #pragma unroll
        for (int m = 0; m < 4; ++m) {
            int row0 = crow0 + m * 16 + lg * 4;
            #pragma unroll
            for (int j = 0; j < 4; ++j) {
                float v = acc[m][n][j] + bv;
                if (relu) v = fmaxf(v, 0.0f);
                size_t idx = (size_t)(row0 + j) * N + col;
                if (Cfp) Cfp[idx] = v;
                if (Cb) Cb[idx] = f2bf(v);
            }
        }
    }
}

// ---------------------------------------------------------------------------
// Flash attention with scalar-slope ALiBi.
// Grid: B*H*(SEQ/64) blocks, 256 threads (4 waves x 16 q-rows).
// ---------------------------------------------------------------------------
__global__ __launch_bounds__(256, 2)
void attn_alibi(const unsigned short* __restrict__ qkv,
                unsigned short* __restrict__ out,
                float slope)
{
    const int qt = blockIdx.x & 15;
    const int bh = blockIdx.x >> 4;
    const int h  = bh & (N_HEADS - 1);
    const int b  = bh >> 4;
    const int w  = threadIdx.x >> 6, l = threadIdx.x & 63;
    const int lr = l & 15, lg = l >> 4;

    __shared__ __align__(16) unsigned short lsK[64 * 64];
    __shared__ __align__(16) unsigned short lsVt[64 * 64];
    __shared__ __align__(16) unsigned short lsP[4 * 16 * 64];

    const size_t rs = 3 * D_MODEL;
    const unsigned short* base = qkv + (size_t)b * SEQ * rs;
    const int qrow_w = qt * 64 + w * 16;
    const float scale = 0.125f;   // 1/sqrt(64)

    bf16x8 aq[2];
    #pragma unroll
    for (int ks = 0; ks < 2; ++ks)
        aq[ks] = *(const bf16x8*)(base + (size_t)(qrow_w + lr) * rs + h * HEAD_DIM + ks * 32 + lg * 8);

    float m_run[4] = {-1e30f, -1e30f, -1e30f, -1e30f};
    float s_run[4] = {0.f, 0.f, 0.f, 0.f};
    f32x4 oacc[4] = {};

    for (int kt = 0; kt < SEQ / 64; ++kt) {
        #pragma unroll
        for (int i = 0; i < 2; ++i) {
            int chunk = i * 4 + w;            // 0..7
            int e = chunk * 512 + l * 8;
            int row = e >> 6, c = e & 63;
            int gcol = c ^ ((row & 7) << 3);  // 8-elem-block XOR swizzle
            gll16(base + (size_t)(kt * 64 + row) * rs + D_MODEL + h * HEAD_DIM + gcol,
                  &lsK[chunk * 512]);
        }
        #pragma unroll
        for (int i = 0; i < 2; ++i) {
            int oct = i * 4 + w;              // d-octet 0..7
            int kj  = l;                      // 0..63
            u16x8 v = *(const u16x8*)(base + (size_t)(kt * 64 + kj) * rs + 2 * D_MODEL + h * HEAD_DIM + oct * 8);
            #pragma unroll
            for (int jj = 0; jj < 8; ++jj) {
                int row = oct * 8 + jj;       // d index
                lsVt[row * 64 + (kj ^ ((row & 7) << 3))] = v[jj];
            }
        }
        __syncthreads();

        f32x4 sacc[4] = {};
        #pragma unroll
        for (int ks = 0; ks < 2; ++ks) {
            #pragma unroll
            for (int n = 0; n < 4; ++n) {
                int row = n * 16 + lr;
                bf16x8 bk = *(const bf16x8*)&lsK[row * 64 + ((ks * 32 + lg * 8) ^ ((row & 7) << 3))];
                sacc[n] = __builtin_amdgcn_mfma_f32_16x16x32_bf16(aq[ks], bk, sacc[n], 0, 0, 0);
            }
        }

        #pragma unroll
        for (int j = 0; j < 4; ++j) {
            float qi = (float)(qt * 64 + w * 16 + lg * 4 + j);
            float sv[4]; float mx = -1e30f;
            #pragma unroll
            for (int n = 0; n < 4; ++n) {
                float kjf = (float)(kt * 64 + n * 16 + lr);
                float val = sacc[n][j] * scale - slope * fabsf(qi - kjf);
                sv[n] = val;
                mx = fmaxf(mx, val);
            }
            #pragma unroll
            for (int d = 1; d < 16; d <<= 1)
                mx = fmaxf(mx, __shfl_xor(mx, d));
            float mnew = fmaxf(m_run[j], mx);
            float corr = __expf(m_run[j] - mnew);
            float psum = 0.f;
            #pragma unroll
            for (int n = 0; n < 4; ++n) {
                float p = __expf(sv[n] - mnew);
                sv[n] = p;
                psum += p;
            }
            #pragma unroll
            for (int d = 1; d < 16; d <<= 1)
                psum += __shfl_xor(psum, d);
            s_run[j] = s_run[j] * corr + psum;
            m_run[j] = mnew;
            #pragma unroll
            for (int nd = 0; nd < 4; ++nd)
                oacc[nd][j] *= corr;
            int prow = lg * 4 + j;
            #pragma unroll
            for (int n = 0; n < 4; ++n)
                lsP[w * 1024 + prow * 64 + ((n * 16 + lr) ^ ((prow & 7) << 3))] = f2bf(sv[n]);
        }

        #pragma unroll
        for (int ks = 0; ks < 2; ++ks) {
            bf16x8 ap = *(const bf16x8*)&lsP[w * 1024 + lr * 64 + ((ks * 32 + lg * 8) ^ ((lr & 7) << 3))];
            #pragma unroll
            for (int nd = 0; nd < 4; ++nd) {
                int row = nd * 16 + lr;
                bf16x8 bv = *(const bf16x8*)&lsVt[row * 64 + ((ks * 32 + lg * 8) ^ ((row & 7) << 3))];
                oacc[nd] = __builtin_amdgcn_mfma_f32_16x16x32_bf16(ap, bv, oacc[nd], 0, 0, 0);
            }
        }
        __syncthreads();
    }

    #pragma unroll
    for (int j = 0; j < 4; ++j) {
        float inv = 1.0f / s_run[j];
        int qrow = qrow_w + lg * 4 + j;
        #pragma unroll
        for (int nd = 0; nd < 4; ++nd) {
            int d = nd * 16 + lr;
            out[((size_t)b * SEQ + qrow) * D_MODEL + h * HEAD_DIM + d] = f2bf(oacc[nd][j] * inv);
        }
    }
}

// ---------------------------------------------------------------------------
// h = LN(resid + sum_p delta[p]) * g + beta ; writes f32 and bf16 views.
// ---------------------------------------------------------------------------
__global__ __launch_bounds__(256)
void add_ln(const float* __restrict__ resid, const float* __restrict__ delta,
            size_t slab, int nslab,
            const float* __restrict__ g, const float* __restrict__ beta,
            float* __restrict__ out_f, unsigned short* __restrict__ out_b)
{
    const int row = blockIdx.x;
    const int t = threadIdx.x;
    const int w = t >> 6, l = t & 63;
    __shared__ float red[8];
    const size_t off = (size_t)row * D_MODEL + t * 4;

    float4 rv = *(const float4*)(resid + off);
    float x0 = rv.x, x1 = rv.y, x2 = rv.z, x3 = rv.w;
    for (int p = 0; p < nslab; ++p) {
        float4 dv = *(const float4*)(delta + p * slab + off);
        x0 += dv.x; x1 += dv.y; x2 += dv.z; x3 += dv.w;
    }
    float s  = x0 + x1 + x2 + x3;
    float s2 = x0 * x0 + x1 * x1 + x2 * x2 + x3 * x3;
    #pragma unroll
    for (int d = 1; d < 64; d <<= 1) {
        s  += __shfl_xor(s, d);
        s2 += __shfl_xor(s2, d);
    }
    if (l == 0) { red[w] = s; red[4 + w] = s2; }
    __syncthreads();
    s  = red[0] + red[1] + red[2] + red[3];
    s2 = red[4] + red[5] + red[6] + red[7];
    float mu  = s * (1.0f / D_MODEL);
    float var = s2 * (1.0f / D_MODEL) - mu * mu;
    float rsq = rsqrtf(var + 1e-5f);

    float4 gv = *(const float4*)(g + t * 4);
    float4 bv = *(const float4*)(beta + t * 4);
    float y0 = (x0 - mu) * rsq * gv.x + bv.x;
    float y1 = (x1 - mu) * rsq * gv.y + bv.y;
    float y2 = (x2 - mu) * rsq * gv.z + bv.z;
    float y3 = (x3 - mu) * rsq * gv.w + bv.w;
    float4 of; of.x = y0; of.y = y1; of.z = y2; of.w = y3;
    *(float4*)(out_f + off) = of;
    ushort4 ob; ob.x = f2bf(y0); ob.y = f2bf(y1); ob.z = f2bf(y2); ob.w = f2bf(y3);
    *(ushort4*)(out_b + off) = ob;
}

// ---------------------------------------------------------------------------
__global__ __launch_bounds__(256)
void head_kernel(const float* __restrict__ h, const float* __restrict__ hw,
                 const float* __restrict__ hb, float* __restrict__ out)
{
    const int wv = threadIdx.x >> 6, l = threadIdx.x & 63;
    const float* hr = h + ((size_t)wv * SEQ + (SEQ - 1)) * D_MODEL;
    for (int c = 0; c < N_CLS; ++c) {
        float s = 0.f;
        for (int k = l; k < D_MODEL; k += 64)
            s += hr[k] * hw[c * D_MODEL + k];
        #pragma unroll
        for (int d = 1; d < 64; d <<= 1)
            s += __shfl_xor(s, d);
        if (l == 0) out[wv * N_CLS + c] = s + hb[c];
    }
}

// ---------------------------------------------------------------------------
extern "C" void kernel_launch(void* const* d_in, const int* in_sizes, int n_in,
                              void* d_out, int out_size, void* d_ws, size_t ws_size,
                              hipStream_t stream)
{
    const float* x     = (const float*)d_in[0];
    const float* in_w  = (const float*)d_in[1];
    const float* in_b  = (const float*)d_in[2];
    const float* Wqkv  = (const float*)d_in[3];
    const float* bqkv  = (const float*)d_in[4];
    const float* Wo    = (const float*)d_in[5];
    const float* bo    = (const float*)d_in[6];
    const float* ln1g  = (const float*)d_in[7];
    const float* ln1b  = (const float*)d_in[8];
    const float* ln2g  = (const float*)d_in[9];
    const float* ln2b  = (const float*)d_in[10];
    const float* W1    = (const float*)d_in[11];
    const float* b1    = (const float*)d_in[12];
    const float* W2    = (const float*)d_in[13];
    const float* b2    = (const float*)d_in[14];
    const float* headw = (const float*)d_in[15];
    const float* headb = (const float*)d_in[16];
    float* out = (float*)d_out;

    char* ws = (char*)d_ws;
    size_t off = 0;
    auto alloc = [&](size_t bytes) -> void* {
        void* p = ws + off;
        off += (bytes + 255) & ~(size_t)255;
        return p;
    };
    const int MT = BATCH * SEQ;  // 4096
    const size_t SLAB = (size_t)MT * D_MODEL;

    unsigned short* x_bf   = (unsigned short*)alloc((size_t)MT * IN_DIM * 2);
    float*          h_f    = (float*)alloc(SLAB * 4);
    unsigned short* h_bf   = (unsigned short*)alloc(SLAB * 2);
    unsigned short* qkv_bf = (unsigned short*)alloc((size_t)MT * 3 * D_MODEL * 2);
    unsigned short* att_bf = (unsigned short*)alloc(SLAB * 2);
    unsigned short* ff_bf  = (unsigned short*)alloc((size_t)MT * FF_DIM * 2);
    float*          tmp_f  = (float*)alloc(SLAB * 4 * 2);   // 2 split-K slabs
    unsigned short* win_bf = (unsigned short*)alloc((size_t)D_MODEL * IN_DIM * 2);
    unsigned short* wq_bf  = (unsigned short*)alloc((size_t)3 * D_MODEL * D_MODEL * 2);
    unsigned short* wo_bf  = (unsigned short*)alloc((size_t)D_MODEL * D_MODEL * 2);
    unsigned short* w1_bf  = (unsigned short*)alloc((size_t)FF_DIM * D_MODEL * 2);
    unsigned short* w2_bf  = (unsigned short*)alloc((size_t)D_MODEL * FF_DIM * 2);

    double ssum = 0.0;
    for (int i = 1; i <= N_HEADS; ++i) ssum += pow(2.0, -8.0 * i / N_HEADS);
    const float slope = (float)(ssum / N_HEADS);

    auto cvt = [&](const float* s, unsigned short* d, int n) {
        cvt_f32_bf16<<<n / 1024, 256, 0, stream>>>(s, d, n);
    };

    // input projection (K=256, full output both views)
    cvt(x, x_bf, MT * IN_DIM);
    cvt(in_w, win_bf, D_MODEL * IN_DIM);
    gemm_bt<<<dim3((MT / 128) * (D_MODEL / 128), 1), 256, 0, stream>>>(
        x_bf, win_bf, in_b, h_f, h_bf, D_MODEL, IN_DIM, IN_DIM, 0, 0);

    for (int layer = 0; layer < N_LAYERS; ++layer) {
        cvt(Wqkv + (size_t)layer * 3 * D_MODEL * D_MODEL, wq_bf, 3 * D_MODEL * D_MODEL);
        cvt(Wo   + (size_t)layer * D_MODEL * D_MODEL,     wo_bf, D_MODEL * D_MODEL);
        cvt(W1   + (size_t)layer * FF_DIM * D_MODEL,      w1_bf, FF_DIM * D_MODEL);
        cvt(W2   + (size_t)layer * D_MODEL * FF_DIM,      w2_bf, D_MODEL * FF_DIM);

        // QKV: M=4096, N=3072, K=1024 (grid 768, no split)
        gemm_bt<<<dim3((MT / 128) * (3 * D_MODEL / 128), 1), 256, 0, stream>>>(
            h_bf, wq_bf, bqkv + (size_t)layer * 3 * D_MODEL,
            nullptr, qkv_bf, 3 * D_MODEL, D_MODEL, D_MODEL, 0, 0);

        attn_alibi<<<BATCH * N_HEADS * (SEQ / 64), 256, 0, stream>>>(qkv_bf, att_bf, slope);

        // Wo: M=4096, N=1024, K=1024 split-K x2 -> grid 512
        gemm_bt<<<dim3((MT / 128) * (D_MODEL / 128), 2), 256, 0, stream>>>(
            att_bf, wo_bf, bo + (size_t)layer * D_MODEL,
            tmp_f, nullptr, D_MODEL, D_MODEL, D_MODEL / 2, 0, SLAB);

        add_ln<<<MT, 256, 0, stream>>>(h_f, tmp_f, SLAB, 2,
            ln1g + (size_t)layer * D_MODEL, ln1b + (size_t)layer * D_MODEL, h_f, h_bf);

        // FF1: M=4096, N=4096, K=1024 (grid 1024, ReLU)
        gemm_bt<<<dim3((MT / 128) * (FF_DIM / 128), 1), 256, 0, stream>>>(
            h_bf, w1_bf, b1 + (size_t)layer * FF_DIM,
            nullptr, ff_bf, FF_DIM, D_MODEL, D_MODEL, 1, 0);

        // FF2: M=4096, N=1024, K=4096 split-K x2 -> grid 512
        gemm_bt<<<dim3((MT / 128) * (D_MODEL / 128), 2), 256, 0, stream>>>(
            ff_bf, w2_bf, b2 + (size_t)layer * D_MODEL,
            tmp_f, nullptr, D_MODEL, FF_DIM, FF_DIM / 2, 0, SLAB);

        add_ln<<<MT, 256, 0, stream>>>(h_f, tmp_f, SLAB, 2,
            ln2g + (size_t)layer * D_MODEL, ln2b + (size_t)layer * D_MODEL, h_f, h_bf);
    }

    head_kernel<<<1, 256, 0, stream>>>(h_f, headw, headb, out);
}

// Round 4
// 1733.184 us; speedup vs baseline: 1.1217x; 1.0954x over previous
//
#include <hip/hip_runtime.h>
#include <cmath>

#define D_MODEL 1024
#define N_HEADS 16
#define HEAD_DIM 64
#define SEQ 1024
#define BATCH 4
#define FF_DIM 4096
#define IN_DIM 256
#define N_LAYERS 6
#define N_CLS 10

typedef __bf16 bf16x8 __attribute__((ext_vector_type(8)));
typedef float f32x4 __attribute__((ext_vector_type(4)));
typedef unsigned short u16x8 __attribute__((ext_vector_type(8)));

__device__ __forceinline__ unsigned short f2bf(float f) {
    unsigned int u = __float_as_uint(f);
    u += 0x7fffu + ((u >> 16) & 1u);
    return (unsigned short)(u >> 16);
}

__device__ __forceinline__ void gll16(const void* g, void* l) {
    __builtin_amdgcn_global_load_lds((const __attribute__((address_space(1))) void*)g,
                                     (__attribute__((address_space(3))) void*)l, 16, 0, 0);
}

// ---------------------------------------------------------------------------
// f32 -> bf16 convert (vectorized)
// ---------------------------------------------------------------------------
__global__ __launch_bounds__(256)
void cvt_f32_bf16(const float* __restrict__ src, unsigned short* __restrict__ dst, int n) {
    int i = (blockIdx.x * 256 + threadIdx.x) * 4;
    if (i + 4 <= n) {
        float4 v = *(const float4*)(src + i);
        ushort4 o;
        o.x = f2bf(v.x); o.y = f2bf(v.y); o.z = f2bf(v.z); o.w = f2bf(v.w);
        *(ushort4*)(dst + i) = o;
    }
}

// ---------------------------------------------------------------------------
// 256x256 8-phase NT GEMM (plain-HIP port of the m201 schedule).
// A[M][lda], B[N][lda] bf16 row-major; C = A*B^T + bias; optional relu,
// f32/bf16 outputs, split-K via blockIdx.y.
// 8 waves (2M x 4N), per-wave 128x64 output. BK=64.
// LDS: k-major slabs [256 rows][32 k] per (matrix, buf, khalf) = 8x16KB=128KB.
// Swizzle: 16B granule p = lg ^ ((row>>1)&3)  (conflict-free col-slice b128),
// applied on the per-lane GLOBAL source (gll16 dest stays linear — rule 21).
// Staging: thread covers granules G0=w*128+l (row r=G0>>2) and G0+64 (row
// r+16): dest d and d+512 elements, source s and s+16*lda. Swizzle term
// ((r>>1)&3) is invariant under +16 rows, so one lg0 serves both.
// Phase = (mu-half x k-half): 16 MFMA; stages 1 half-slab; vmcnt(4) @ ph4/ph8.
// ---------------------------------------------------------------------------
template<int MU, bool LOADB, bool GATE, typename F>
__device__ __forceinline__
void gphase(f32x4 (&acc)[8][4], bf16x8 (&bfr)[4],
            const unsigned short* slabA, const unsigned short* slabB,
            const int (&aoff)[2][4], const int (&boff)[4], F&& stage, bool gate0)
{
    bf16x8 afr[4];
    if (LOADB) {
        _Pragma("unroll")
        for (int n = 0; n < 4; ++n) bfr[n] = *(const bf16x8*)(slabB + boff[n]);
    }
    _Pragma("unroll")
    for (int m = 0; m < 4; ++m) afr[m] = *(const bf16x8*)(slabA + aoff[MU][m]);
    stage();
    __builtin_amdgcn_s_barrier();
    asm volatile("s_waitcnt lgkmcnt(0)" ::: "memory");
    __builtin_amdgcn_sched_barrier(0);
    __builtin_amdgcn_s_setprio(1);
    _Pragma("unroll")
    for (int m = 0; m < 4; ++m)
        _Pragma("unroll")
        for (int n = 0; n < 4; ++n)
            acc[MU * 4 + m][n] =
                __builtin_amdgcn_mfma_f32_16x16x32_bf16(afr[m], bfr[n], acc[MU * 4 + m][n], 0, 0, 0);
    __builtin_amdgcn_s_setprio(0);
    if (GATE) {
        if (gate0) asm volatile("s_waitcnt vmcnt(0)" ::: "memory");
        else       asm volatile("s_waitcnt vmcnt(4)" ::: "memory");
    }
    __builtin_amdgcn_s_barrier();
}

__global__ __launch_bounds__(512, 2)
void gemm256(const unsigned short* __restrict__ A, const unsigned short* __restrict__ B,
             const float* __restrict__ bias,
             float* __restrict__ Cf, unsigned short* __restrict__ Cb,
             int N, int lda, int klen, int relu, size_t slab_stride)
{
    extern __shared__ unsigned short lds[];   // 131072 B
    auto slA = [&](int buf, int kh) { return lds + (buf * 2 + kh) * 8192; };
    auto slB = [&](int buf, int kh) { return lds + 32768 + (buf * 2 + kh) * 8192; };

    const int nbc = N >> 8;
    const int nwg = gridDim.x;
    const int orig = blockIdx.x;
    const int xcd = orig & 7, lid = orig >> 3;
    const int q = nwg >> 3, r = nwg & 7;
    const int wgid = (xcd < r ? xcd * (q + 1) : r * (q + 1) + (xcd - r) * q) + lid;
    const int brow = wgid / nbc, bcol = wgid % nbc;
    const int kpart = blockIdx.y;

    const int tid = threadIdx.x;
    const int w = tid >> 6, l = tid & 63;
    const int wr = w >> 2, wc = w & 3;
    const int lr = l & 15, lg4 = l >> 4;

    const unsigned short* Ab = A + (size_t)brow * 256 * lda + (size_t)kpart * klen;
    const unsigned short* Bb = B + (size_t)bcol * 256 * lda + (size_t)kpart * klen;
    float* Cfp = Cf ? Cf + (size_t)kpart * slab_stride : nullptr;
    const float* biasp = (kpart == 0) ? bias : nullptr;

    // --- staging constants: thread handles granules G0 (row tr0) and G0+64
    // (row tr0+16); bit6(G0)==0 so the two writes tile all 1024 granules.
    const int G0 = w * 128 + l;
    const int tr0 = G0 >> 2;
    const int lg0 = (G0 & 3) ^ ((tr0 >> 1) & 3);

    auto stA = [&](int buf, int kh, int tile) {
        unsigned short* d = slA(buf, kh) + G0 * 8;
        const unsigned short* s = Ab + (size_t)tr0 * lda + tile * 64 + kh * 32 + lg0 * 8;
        gll16(s, d);
        gll16(s + (size_t)16 * lda, d + 512);
    };
    auto stB = [&](int buf, int kh, int tile) {
        unsigned short* d = slB(buf, kh) + G0 * 8;
        const unsigned short* s = Bb + (size_t)tr0 * lda + tile * 64 + kh * 32 + lg0 * 8;
        gll16(s, d);
        gll16(s + (size_t)16 * lda, d + 512);
    };

    // --- fragment read offsets (elements within a slab), swizzled
    int aoff[2][4], boff[4];
    #pragma unroll
    for (int mu = 0; mu < 2; ++mu)
        #pragma unroll
        for (int m = 0; m < 4; ++m) {
            int tA = wr * 128 + mu * 64 + m * 16 + lr;
            aoff[mu][m] = tA * 32 + ((lg4 ^ ((tA >> 1) & 3)) << 3);
        }
    #pragma unroll
    for (int n = 0; n < 4; ++n) {
        int tB = wc * 64 + n * 16 + lr;
        boff[n] = tB * 32 + ((lg4 ^ ((tB >> 1) & 3)) << 3);
    }

    f32x4 acc[8][4] = {};

    const int KT = klen >> 6;
    // prologue: stage tiles 0 (buf0) and 1 (buf1) fully, drain
    stA(0, 0, 0); stA(0, 1, 0); stB(0, 0, 0); stB(0, 1, 0);
    if (KT > 1) { stA(1, 0, 1); stA(1, 1, 1); stB(1, 0, 1); stB(1, 1, 1); }
    asm volatile("s_waitcnt vmcnt(0)" ::: "memory");
    __builtin_amdgcn_s_barrier();

    for (int I = 0; I < KT / 2; ++I) {
        const int t2 = 2 * I;
        const bool s12 = (I > 0);
        const bool more = (t2 + 2 < KT);
        bf16x8 bfr[4];
        gphase<0, true , false>(acc, bfr, slA(0,0), slB(0,0), aoff, boff, [&]{ if (s12)  stA(1,1,t2+1); }, false);
        gphase<1, false, false>(acc, bfr, slA(0,0), slB(0,0), aoff, boff, [&]{ if (s12)  stB(1,1,t2+1); }, false);
        gphase<0, true , false>(acc, bfr, slA(0,1), slB(0,1), aoff, boff, [&]{ if (more) stA(0,0,t2+2); }, false);
        gphase<1, false, true >(acc, bfr, slA(0,1), slB(0,1), aoff, boff, [&]{ if (more) stB(0,0,t2+2); }, !more);
        gphase<0, true , false>(acc, bfr, slA(1,0), slB(1,0), aoff, boff, [&]{ if (more) stA(0,1,t2+2); }, false);
        gphase<1, false, false>(acc, bfr, slA(1,0), slB(1,0), aoff, boff, [&]{ if (more) stB(0,1,t2+2); }, false);
        gphase<0, true , false>(acc, bfr, slA(1,1), slB(1,1), aoff, boff, [&]{ if (more) stA(1,0,t2+3); }, false);
        gphase<1, false, true >(acc, bfr, slA(1,1), slB(1,1), aoff, boff, [&]{ if (more) stB(1,0,t2+3); }, !more);
    }

    // --- epilogue
    const int crow0 = brow * 256 + wr * 128;
    const int ccol0 = bcol * 256 + wc * 64;
    #pragma unroll
    for (int n = 0; n < 4; ++n) {
        int col = ccol0 + n * 16 + lr;
        float bv = biasp ? biasp[col] : 0.0f;
        #pragma unroll
        for (int m = 0; m < 8; ++m) {
            int row0 = crow0 + m * 16 + lg4 * 4;
            #pragma unroll
            for (int j = 0; j < 4; ++j) {
                float v = acc[m][n][j] + bv;
                if (relu) v = fmaxf(v, 0.0f);
                size_t idx = (size_t)(row0 + j) * N + col;
                if (Cfp) Cfp[idx] = v;
                if (Cb) Cb[idx] = f2bf(v);
            }
        }
    }
}

// ---------------------------------------------------------------------------
// Flash attention with scalar-slope ALiBi (XCD-chunked bid).
// ---------------------------------------------------------------------------
__global__ __launch_bounds__(256, 2)
void attn_alibi(const unsigned short* __restrict__ qkv,
                unsigned short* __restrict__ out,
                float slope)
{
    const int bid = blockIdx.x;
    const int id = (bid & 7) * 128 + (bid >> 3);
    const int qt = id & 15;
    const int bh = id >> 4;
    const int h  = bh & (N_HEADS - 1);
    const int b  = bh >> 4;
    const int w  = threadIdx.x >> 6, l = threadIdx.x & 63;
    const int lr = l & 15, lg = l >> 4;

    __shared__ __align__(16) unsigned short lsK[64 * 64];
    __shared__ __align__(16) unsigned short lsVt[64 * 64];
    __shared__ __align__(16) unsigned short lsP[4 * 16 * 64];

    const size_t rs = 3 * D_MODEL;
    const unsigned short* base = qkv + (size_t)b * SEQ * rs;
    const int qrow_w = qt * 64 + w * 16;
    const float scale = 0.125f;

    bf16x8 aq[2];
    #pragma unroll
    for (int ks = 0; ks < 2; ++ks)
        aq[ks] = *(const bf16x8*)(base + (size_t)(qrow_w + lr) * rs + h * HEAD_DIM + ks * 32 + lg * 8);

    float m_run[4] = {-1e30f, -1e30f, -1e30f, -1e30f};
    float s_run[4] = {0.f, 0.f, 0.f, 0.f};
    f32x4 oacc[4] = {};

    for (int kt = 0; kt < SEQ / 64; ++kt) {
        #pragma unroll
        for (int i = 0; i < 2; ++i) {
            int chunk = i * 4 + w;
            int e = chunk * 512 + l * 8;
            int row = e >> 6, c = e & 63;
            int gcol = c ^ ((row & 7) << 3);
            gll16(base + (size_t)(kt * 64 + row) * rs + D_MODEL + h * HEAD_DIM + gcol,
                  &lsK[chunk * 512]);
        }
        #pragma unroll
        for (int i = 0; i < 2; ++i) {
            int oct = i * 4 + w;
            int kj  = l;
            u16x8 v = *(const u16x8*)(base + (size_t)(kt * 64 + kj) * rs + 2 * D_MODEL + h * HEAD_DIM + oct * 8);
            #pragma unroll
            for (int jj = 0; jj < 8; ++jj) {
                int row = oct * 8 + jj;
                lsVt[row * 64 + (kj ^ ((row & 7) << 3))] = v[jj];
            }
        }
        __syncthreads();

        f32x4 sacc[4] = {};
        #pragma unroll
        for (int ks = 0; ks < 2; ++ks) {
            #pragma unroll
            for (int n = 0; n < 4; ++n) {
                int row = n * 16 + lr;
                bf16x8 bk = *(const bf16x8*)&lsK[row * 64 + ((ks * 32 + lg * 8) ^ ((row & 7) << 3))];
                sacc[n] = __builtin_amdgcn_mfma_f32_16x16x32_bf16(aq[ks], bk, sacc[n], 0, 0, 0);
            }
        }

        #pragma unroll
        for (int j = 0; j < 4; ++j) {
            float qi = (float)(qt * 64 + w * 16 + lg * 4 + j);
            float sv[4]; float mx = -1e30f;
            #pragma unroll
            for (int n = 0; n < 4; ++n) {
                float kjf = (float)(kt * 64 + n * 16 + lr);
                float val = sacc[n][j] * scale - slope * fabsf(qi - kjf);
                sv[n] = val;
                mx = fmaxf(mx, val);
            }
            #pragma unroll
            for (int d = 1; d < 16; d <<= 1)
                mx = fmaxf(mx, __shfl_xor(mx, d));
            float mnew = fmaxf(m_run[j], mx);
            float corr = __expf(m_run[j] - mnew);
            float psum = 0.f;
            #pragma unroll
            for (int n = 0; n < 4; ++n) {
                float p = __expf(sv[n] - mnew);
                sv[n] = p;
                psum += p;
            }
            #pragma unroll
            for (int d = 1; d < 16; d <<= 1)
                psum += __shfl_xor(psum, d);
            s_run[j] = s_run[j] * corr + psum;
            m_run[j] = mnew;
            #pragma unroll
            for (int nd = 0; nd < 4; ++nd)
                oacc[nd][j] *= corr;
            int prow = lg * 4 + j;
            #pragma unroll
            for (int n = 0; n < 4; ++n)
                lsP[w * 1024 + prow * 64 + ((n * 16 + lr) ^ ((prow & 7) << 3))] = f2bf(sv[n]);
        }

        #pragma unroll
        for (int ks = 0; ks < 2; ++ks) {
            bf16x8 ap = *(const bf16x8*)&lsP[w * 1024 + lr * 64 + ((ks * 32 + lg * 8) ^ ((lr & 7) << 3))];
            #pragma unroll
            for (int nd = 0; nd < 4; ++nd) {
                int row = nd * 16 + lr;
                bf16x8 bv = *(const bf16x8*)&lsVt[row * 64 + ((ks * 32 + lg * 8) ^ ((row & 7) << 3))];
                oacc[nd] = __builtin_amdgcn_mfma_f32_16x16x32_bf16(ap, bv, oacc[nd], 0, 0, 0);
            }
        }
        __syncthreads();
    }

    #pragma unroll
    for (int j = 0; j < 4; ++j) {
        float inv = 1.0f / s_run[j];
        int qrow = qrow_w + lg * 4 + j;
        #pragma unroll
        for (int nd = 0; nd < 4; ++nd) {
            int d = nd * 16 + lr;
            out[((size_t)b * SEQ + qrow) * D_MODEL + h * HEAD_DIM + d] = f2bf(oacc[nd][j] * inv);
        }
    }
}

// ---------------------------------------------------------------------------
// h = LN(resid + sum_p delta[p]) * g + beta ; writes f32 and bf16 views.
// ---------------------------------------------------------------------------
__global__ __launch_bounds__(256)
void add_ln(const float* __restrict__ resid, const float* __restrict__ delta,
            size_t slab, int nslab,
            const float* __restrict__ g, const float* __restrict__ beta,
            float* __restrict__ out_f, unsigned short* __restrict__ out_b)
{
    const int row = blockIdx.x;
    const int t = threadIdx.x;
    const int w = t >> 6, l = t & 63;
    __shared__ float red[8];
    const size_t off = (size_t)row * D_MODEL + t * 4;

    float4 rv = *(const float4*)(resid + off);
    float x0 = rv.x, x1 = rv.y, x2 = rv.z, x3 = rv.w;
    for (int p = 0; p < nslab; ++p) {
        float4 dv = *(const float4*)(delta + p * slab + off);
        x0 += dv.x; x1 += dv.y; x2 += dv.z; x3 += dv.w;
    }
    float s  = x0 + x1 + x2 + x3;
    float s2 = x0 * x0 + x1 * x1 + x2 * x2 + x3 * x3;
    #pragma unroll
    for (int d = 1; d < 64; d <<= 1) {
        s  += __shfl_xor(s, d);
        s2 += __shfl_xor(s2, d);
    }
    if (l == 0) { red[w] = s; red[4 + w] = s2; }
    __syncthreads();
    s  = red[0] + red[1] + red[2] + red[3];
    s2 = red[4] + red[5] + red[6] + red[7];
    float mu  = s * (1.0f / D_MODEL);
    float var = s2 * (1.0f / D_MODEL) - mu * mu;
    float rsq = rsqrtf(var + 1e-5f);

    float4 gv = *(const float4*)(g + t * 4);
    float4 bv = *(const float4*)(beta + t * 4);
    float y0 = (x0 - mu) * rsq * gv.x + bv.x;
    float y1 = (x1 - mu) * rsq * gv.y + bv.y;
    float y2 = (x2 - mu) * rsq * gv.z + bv.z;
    float y3 = (x3 - mu) * rsq * gv.w + bv.w;
    float4 of; of.x = y0; of.y = y1; of.z = y2; of.w = y3;
    *(float4*)(out_f + off) = of;
    ushort4 ob; ob.x = f2bf(y0); ob.y = f2bf(y1); ob.z = f2bf(y2); ob.w = f2bf(y3);
    *(ushort4*)(out_b + off) = ob;
}

// ---------------------------------------------------------------------------
__global__ __launch_bounds__(256)
void head_kernel(const float* __restrict__ h, const float* __restrict__ hw,
                 const float* __restrict__ hb, float* __restrict__ out)
{
    const int wv = threadIdx.x >> 6, l = threadIdx.x & 63;
    const float* hr = h + ((size_t)wv * SEQ + (SEQ - 1)) * D_MODEL;
    for (int c = 0; c < N_CLS; ++c) {
        float s = 0.f;
        for (int k = l; k < D_MODEL; k += 64)
            s += hr[k] * hw[c * D_MODEL + k];
        #pragma unroll
        for (int d = 1; d < 64; d <<= 1)
            s += __shfl_xor(s, d);
        if (l == 0) out[wv * N_CLS + c] = s + hb[c];
    }
}

// ---------------------------------------------------------------------------
extern "C" void kernel_launch(void* const* d_in, const int* in_sizes, int n_in,
                              void* d_out, int out_size, void* d_ws, size_t ws_size,
                              hipStream_t stream)
{
    const float* x     = (const float*)d_in[0];
    const float* in_w  = (const float*)d_in[1];
    const float* in_b  = (const float*)d_in[2];
    const float* Wqkv  = (const float*)d_in[3];
    const float* bqkv  = (const float*)d_in[4];
    const float* Wo    = (const float*)d_in[5];
    const float* bo    = (const float*)d_in[6];
    const float* ln1g  = (const float*)d_in[7];
    const float* ln1b  = (const float*)d_in[8];
    const float* ln2g  = (const float*)d_in[9];
    const float* ln2b  = (const float*)d_in[10];
    const float* W1    = (const float*)d_in[11];
    const float* b1    = (const float*)d_in[12];
    const float* W2    = (const float*)d_in[13];
    const float* b2    = (const float*)d_in[14];
    const float* headw = (const float*)d_in[15];
    const float* headb = (const float*)d_in[16];
    float* out = (float*)d_out;

    hipFuncSetAttribute((const void*)gemm256, hipFuncAttributeMaxDynamicSharedMemorySize, 131072);

    char* ws = (char*)d_ws;
    size_t off = 0;
    auto alloc = [&](size_t bytes) -> void* {
        void* p = ws + off;
        off += (bytes + 255) & ~(size_t)255;
        return p;
    };
    const int MT = BATCH * SEQ;  // 4096
    const size_t SLAB = (size_t)MT * D_MODEL;

    unsigned short* x_bf   = (unsigned short*)alloc((size_t)MT * IN_DIM * 2);
    float*          h_f    = (float*)alloc(SLAB * 4);
    unsigned short* h_bf   = (unsigned short*)alloc(SLAB * 2);
    unsigned short* qkv_bf = (unsigned short*)alloc((size_t)MT * 3 * D_MODEL * 2);
    unsigned short* att_bf = (unsigned short*)alloc(SLAB * 2);
    unsigned short* ff_bf  = (unsigned short*)alloc((size_t)MT * FF_DIM * 2);
    float*          tmp_f  = (float*)alloc(SLAB * 4 * 4);   // 4 split-K slabs
    unsigned short* win_bf = (unsigned short*)alloc((size_t)D_MODEL * IN_DIM * 2);
    unsigned short* wq_bf  = (unsigned short*)alloc((size_t)3 * D_MODEL * D_MODEL * 2);
    unsigned short* wo_bf  = (unsigned short*)alloc((size_t)D_MODEL * D_MODEL * 2);
    unsigned short* w1_bf  = (unsigned short*)alloc((size_t)FF_DIM * D_MODEL * 2);
    unsigned short* w2_bf  = (unsigned short*)alloc((size_t)D_MODEL * FF_DIM * 2);

    double ssum = 0.0;
    for (int i = 1; i <= N_HEADS; ++i) ssum += pow(2.0, -8.0 * i / N_HEADS);
    const float slope = (float)(ssum / N_HEADS);

    auto cvt = [&](const float* s, unsigned short* d, int n) {
        cvt_f32_bf16<<<n / 1024, 256, 0, stream>>>(s, d, n);
    };

    // input projection: M=4096, N=1024, K=256
    cvt(x, x_bf, MT * IN_DIM);
    cvt(in_w, win_bf, D_MODEL * IN_DIM);
    gemm256<<<dim3(16 * 4, 1), 512, 131072, stream>>>(
        x_bf, win_bf, in_b, h_f, h_bf, D_MODEL, IN_DIM, IN_DIM, 0, 0);

    for (int layer = 0; layer < N_LAYERS; ++layer) {
        cvt(Wqkv + (size_t)layer * 3 * D_MODEL * D_MODEL, wq_bf, 3 * D_MODEL * D_MODEL);
        cvt(Wo   + (size_t)layer * D_MODEL * D_MODEL,     wo_bf, D_MODEL * D_MODEL);
        cvt(W1   + (size_t)layer * FF_DIM * D_MODEL,      w1_bf, FF_DIM * D_MODEL);
        cvt(W2   + (size_t)layer * D_MODEL * FF_DIM,      w2_bf, D_MODEL * FF_DIM);

        // QKV: M=4096, N=3072, K=1024 -> 192 blocks
        gemm256<<<dim3(16 * 12, 1), 512, 131072, stream>>>(
            h_bf, wq_bf, bqkv + (size_t)layer * 3 * D_MODEL,
            nullptr, qkv_bf, 3 * D_MODEL, D_MODEL, D_MODEL, 0, 0);

        attn_alibi<<<BATCH * N_HEADS * (SEQ / 64), 256, 0, stream>>>(qkv_bf, att_bf, slope);

        // Wo: M=4096, N=1024, K=1024 split-K x4 -> 256 blocks
        gemm256<<<dim3(16 * 4, 4), 512, 131072, stream>>>(
            att_bf, wo_bf, bo + (size_t)layer * D_MODEL,
            tmp_f, nullptr, D_MODEL, D_MODEL, D_MODEL / 4, 0, SLAB);

        add_ln<<<MT, 256, 0, stream>>>(h_f, tmp_f, SLAB, 4,
            ln1g + (size_t)layer * D_MODEL, ln1b + (size_t)layer * D_MODEL, h_f, h_bf);

        // FF1: M=4096, N=4096, K=1024 -> 256 blocks, ReLU
        gemm256<<<dim3(16 * 16, 1), 512, 131072, stream>>>(
            h_bf, w1_bf, b1 + (size_t)layer * FF_DIM,
            nullptr, ff_bf, FF_DIM, D_MODEL, D_MODEL, 1, 0);

        // FF2: M=4096, N=1024, K=4096 split-K x4 -> 256 blocks
        gemm256<<<dim3(16 * 4, 4), 512, 131072, stream>>>(
            ff_bf, w2_bf, b2 + (size_t)layer * D_MODEL,
            tmp_f, nullptr, D_MODEL, FF_DIM, FF_DIM / 4, 0, SLAB);

        add_ln<<<MT, 256, 0, stream>>>(h_f, tmp_f, SLAB, 4,
            ln2g + (size_t)layer * D_MODEL, ln2b + (size_t)layer * D_MODEL, h_f, h_bf);
    }

    head_kernel<<<1, 256, 0, stream>>>(h_f, headw, headb, out);
}